// Round 1
// baseline (49.266 us; speedup 1.0000x reference)
//
#include <hip/hip_runtime.h>

#define NB 64
#define NT 512
#define HIDDEN 512
#define TARGET_FRAMES 861   // 22050*10/256

// Kernel 1: per batch row, duration = round(clip(p,1,10)); inclusive cumsum -> ends
__global__ __launch_bounds__(NT) void lr_cumsum(const float* __restrict__ pred,
                                                int* __restrict__ ends) {
    __shared__ int s[NT];
    const int b = blockIdx.x;
    const int t = threadIdx.x;
    float p = pred[b * NT + t];
    p = fminf(fmaxf(p, 1.0f), 10.0f);
    int d = (int)rintf(p);          // round half to even, matches jnp.round
    s[t] = d;
    __syncthreads();
    // Hillis-Steele inclusive scan over 512 entries
    for (int off = 1; off < NT; off <<= 1) {
        int v = s[t];
        int add = (t >= off) ? s[t - off] : 0;
        __syncthreads();
        s[t] = v + add;
        __syncthreads();
    }
    ends[b * NT + t] = s[t];
}

// Kernel 2: one block per (b, frame). Binary search ends (wave-uniform),
// then copy one 512-float row as 128 x float4 (or zeros if frame invalid).
__global__ __launch_bounds__(128) void lr_gather(const float* __restrict__ batch,
                                                 const int* __restrict__ ends,
                                                 float* __restrict__ out) {
    const int bf = blockIdx.x;
    const int b = bf / TARGET_FRAMES;
    const int f = bf - b * TARGET_FRAMES;

    const int* e = ends + b * NT;
    const int total = e[NT - 1];

    float4 v = make_float4(0.f, 0.f, 0.f, 0.f);
    if (f < total) {
        // searchsorted(e, f, side='right'): first index with e[idx] > f
        int lo = 0, hi = NT;
        while (lo < hi) {
            int mid = (lo + hi) >> 1;
            if (e[mid] <= f) lo = mid + 1; else hi = mid;
        }
        int idx = min(lo, NT - 1);
        const float4* src =
            (const float4*)(batch + ((size_t)b * NT + idx) * HIDDEN);
        v = src[threadIdx.x];
    }
    float4* dst = (float4*)(out + ((size_t)b * TARGET_FRAMES + f) * HIDDEN);
    dst[threadIdx.x] = v;
}

extern "C" void kernel_launch(void* const* d_in, const int* in_sizes, int n_in,
                              void* d_out, int out_size, void* d_ws, size_t ws_size,
                              hipStream_t stream) {
    const float* batch = (const float*)d_in[0];
    const float* pred  = (const float*)d_in[1];
    float* out = (float*)d_out;
    int* ends = (int*)d_ws;   // NB*NT ints = 128 KB

    lr_cumsum<<<NB, NT, 0, stream>>>(pred, ends);
    lr_gather<<<NB * TARGET_FRAMES, 128, 0, stream>>>(batch, ends, out);
}

// Round 2
// 36.503 us; speedup vs baseline: 1.3496x; 1.3496x over previous
//
#include <hip/hip_runtime.h>

#define NB 64
#define NT 512
#define HIDDEN 512
#define TARGET_FRAMES 861   // 22050*10/256
#define INVALID_IDX 0xFFFFu

// Kernel A: per batch row b:
//   d = round(clip(pred,1,10)); ends = inclusive cumsum(d)  (in LDS)
//   for each frame f in [0,861): idx = searchsorted(ends, f, 'right')
//   idxbuf[b][f] = (f < total) ? min(idx,511) : 0xFFFF   (as u16)
__global__ __launch_bounds__(NT) void lr_prep(const float* __restrict__ pred,
                                              unsigned short* __restrict__ idxbuf) {
    __shared__ int s[NT];
    const int b = blockIdx.x;
    const int t = threadIdx.x;
    float p = pred[b * NT + t];
    p = fminf(fmaxf(p, 1.0f), 10.0f);
    s[t] = (int)rintf(p);           // round half to even == jnp.round
    __syncthreads();
    // Hillis-Steele inclusive scan over 512 entries
    for (int off = 1; off < NT; off <<= 1) {
        int v = s[t];
        int add = (t >= off) ? s[t - off] : 0;
        __syncthreads();
        s[t] = v + add;
        __syncthreads();
    }
    const int total = s[NT - 1];
    // each thread searches up to 2 frames (861 < 2*512)
    for (int f = t; f < TARGET_FRAMES; f += NT) {
        unsigned short r = INVALID_IDX;
        if (f < total) {
            int lo = 0, hi = NT;
            while (lo < hi) {
                int mid = (lo + hi) >> 1;
                if (s[mid] <= f) lo = mid + 1; else hi = mid;
            }
            r = (unsigned short)min(lo, NT - 1);
        }
        idxbuf[b * TARGET_FRAMES + f] = r;
    }
}

// Kernel B: pure streaming gather. One thread per output float4.
// out is [NB][TARGET_FRAMES][HIDDEN] f32 -> NB*861*128 float4s.
__global__ __launch_bounds__(256) void lr_gather(const float4* __restrict__ batch4,
                                                 const unsigned short* __restrict__ idxbuf,
                                                 float4* __restrict__ out4) {
    const int i = blockIdx.x * 256 + threadIdx.x;   // grid sized exactly
    const int fi = i >> 7;                 // b*861 + f  (128 float4 per frame)
    const int c  = i & 127;
    const int b  = fi / TARGET_FRAMES;     // magic-mul division by constant
    const unsigned int idx = idxbuf[fi];   // uniform per 128-thread group, L2-hot
    float4 v = make_float4(0.f, 0.f, 0.f, 0.f);
    if (idx != INVALID_IDX)
        v = batch4[(((size_t)b * NT + idx) << 7) + c];
    out4[i] = v;
}

extern "C" void kernel_launch(void* const* d_in, const int* in_sizes, int n_in,
                              void* d_out, int out_size, void* d_ws, size_t ws_size,
                              hipStream_t stream) {
    const float* batch = (const float*)d_in[0];
    const float* pred  = (const float*)d_in[1];
    float* out = (float*)d_out;
    unsigned short* idxbuf = (unsigned short*)d_ws;   // NB*861 u16 = 110 KB

    lr_prep<<<NB, NT, 0, stream>>>(pred, idxbuf);

    const int total4 = NB * TARGET_FRAMES * (HIDDEN / 4);   // 7,053,312
    lr_gather<<<total4 / 256, 256, 0, stream>>>((const float4*)batch, idxbuf,
                                                (float4*)out);
}

// Round 3
// 30.152 us; speedup vs baseline: 1.6339x; 1.2106x over previous
//
#include <hip/hip_runtime.h>

#define NB 64
#define NT 512
#define HIDDEN 512
#define TARGET_FRAMES 861   // 22050*10/256
#define INVALID_IDX 0xFFFFu
#define NFRAMES (NB * TARGET_FRAMES)          // 55104
#define GATHER_BLOCKS (NFRAMES / 4)           // 13776, divisible by 8

// Kernel A: per batch row: d = round(clip(pred,1,10)); ends = cumsum(d);
// idxbuf[b][f] = searchsorted(ends, f, 'right') clamped, 0xFFFF if f >= total.
__global__ __launch_bounds__(NT) void lr_prep(const float* __restrict__ pred,
                                              unsigned short* __restrict__ idxbuf) {
    __shared__ int s[NT];
    __shared__ int wsum[NT / 64];
    const int b = blockIdx.x;
    const int t = threadIdx.x;
    const int lane = t & 63;
    const int wid = t >> 6;

    float p = fminf(fmaxf(pred[b * NT + t], 1.0f), 10.0f);
    int x = (int)rintf(p);          // round-half-to-even == jnp.round
    // per-wave inclusive scan via shuffles (no barriers)
    #pragma unroll
    for (int off = 1; off < 64; off <<= 1) {
        int y = __shfl_up(x, off, 64);
        if (lane >= off) x += y;
    }
    if (lane == 63) wsum[wid] = x;
    __syncthreads();
    int prefix = 0;
    #pragma unroll
    for (int w = 0; w < NT / 64; ++w)
        if (w < wid) prefix += wsum[w];   // LDS broadcast reads
    x += prefix;
    s[t] = x;
    __syncthreads();

    const int total = s[NT - 1];
    for (int f = t; f < TARGET_FRAMES; f += NT) {
        unsigned short r = INVALID_IDX;
        if (f < total) {
            int lo = 0, hi = NT;
            while (lo < hi) {
                int mid = (lo + hi) >> 1;
                if (s[mid] <= f) lo = mid + 1; else hi = mid;
            }
            r = (unsigned short)min(lo, NT - 1);
        }
        idxbuf[b * TARGET_FRAMES + f] = r;
    }
}

// Kernel B: one wave per frame (4 frames / 256-thread block).
// Each thread moves 2 float4 (32 B). XCD-chunked block swizzle keeps a
// contiguous frame range (and thus a small row working set) on one XCD's L2.
__global__ __launch_bounds__(256) void lr_gather(const float4* __restrict__ batch4,
                                                 const unsigned short* __restrict__ idxbuf,
                                                 float4* __restrict__ out4) {
    const int bid = blockIdx.x;
    // bijective: GATHER_BLOCKS % 8 == 0
    const int swz = (bid & 7) * (GATHER_BLOCKS >> 3) + (bid >> 3);
    const int wave = threadIdx.x >> 6;
    const int lane = threadIdx.x & 63;
    const int fi = swz * 4 + wave;            // global frame id = b*861 + f
    const int b = fi / TARGET_FRAMES;

    const unsigned int idx = idxbuf[fi];      // wave-uniform, L1/L2-hot
    float4 v0 = make_float4(0.f, 0.f, 0.f, 0.f);
    float4 v1 = v0;
    if (idx != INVALID_IDX) {
        const float4* src = batch4 + (((size_t)b * NT + idx) << 7);
        v0 = src[lane];
        v1 = src[lane + 64];
    }
    float4* dst = out4 + ((size_t)fi << 7);
    dst[lane] = v0;
    dst[lane + 64] = v1;
}

extern "C" void kernel_launch(void* const* d_in, const int* in_sizes, int n_in,
                              void* d_out, int out_size, void* d_ws, size_t ws_size,
                              hipStream_t stream) {
    const float* batch = (const float*)d_in[0];
    const float* pred  = (const float*)d_in[1];
    float* out = (float*)d_out;
    unsigned short* idxbuf = (unsigned short*)d_ws;   // NFRAMES u16 = 110 KB

    lr_prep<<<NB, NT, 0, stream>>>(pred, idxbuf);
    lr_gather<<<GATHER_BLOCKS, 256, 0, stream>>>((const float4*)batch, idxbuf,
                                                 (float4*)out);
}

// Round 4
// 27.653 us; speedup vs baseline: 1.7816x; 1.0904x over previous
//
#include <hip/hip_runtime.h>

#define NB 64
#define NT 512
#define HIDDEN 512
#define TF 861            // 22050*10/256
#define CHUNKS 32
#define FPC 27            // ceil(861/32); last chunk has 24
#define GRID (NB * CHUNKS)   // 2048, divisible by 8

// One fused kernel. Each block: redundantly scan its batch row's durations
// (cheap, L2-hot), searchsorted its 27 frames, then stream-copy 27 rows.
__global__ __launch_bounds__(256) void lr_fused(const float* __restrict__ pred,
                                                const float4* __restrict__ batch4,
                                                float4* __restrict__ out4) {
    __shared__ int s[NT];
    __shared__ int wsum[4];
    __shared__ int sidx[FPC];

    // XCD-chunked swizzle: XCD k owns a contiguous range of (b,chunk) pairs
    const int bid = blockIdx.x;
    const int sid = (bid & 7) * (GRID >> 3) + (bid >> 3);
    const int b = sid >> 5;           // CHUNKS == 32
    const int chunk = sid & 31;
    const int base = chunk * FPC;

    const int t = threadIdx.x;
    const int lane = t & 63;
    const int wid = t >> 6;

    // ---- duration scan: 512 entries, 2 per thread ----
    float2 p2 = ((const float2*)(pred + b * NT))[t];
    int d0 = (int)rintf(fminf(fmaxf(p2.x, 1.f), 10.f));   // round-half-even
    int d1 = (int)rintf(fminf(fmaxf(p2.y, 1.f), 10.f));
    int x = d0 + d1;
    #pragma unroll
    for (int off = 1; off < 64; off <<= 1) {
        int y = __shfl_up(x, off, 64);
        if (lane >= off) x += y;
    }
    if (lane == 63) wsum[wid] = x;
    __syncthreads();
    int prefix = 0;
    #pragma unroll
    for (int w = 0; w < 3; ++w)
        if (w < wid) prefix += wsum[w];
    x += prefix;
    s[2 * t]     = x - d1;   // inclusive cumsum at element 2t
    s[2 * t + 1] = x;        // and 2t+1
    __syncthreads();

    const int total = s[NT - 1];

    // ---- searchsorted(ends, f, 'right') for this chunk's frames ----
    if (t < FPC) {
        int f = base + t;
        int r = -1;
        if (f < TF && f < total) {
            int lo = 0, hi = NT;
            while (lo < hi) {
                int mid = (lo + hi) >> 1;
                if (s[mid] <= f) lo = mid + 1; else hi = mid;
            }
            r = min(lo, NT - 1);
        }
        sidx[t] = r;
    }
    __syncthreads();

    // ---- streaming copy: 2 frames (4 KB) per iteration ----
    const int c = t & 127;
    const int half = t >> 7;
    const float4* srcb = batch4 + ((size_t)b << 16);   // b*512*128
    #pragma unroll 2
    for (int fo = half; fo < FPC; fo += 2) {
        const int f = base + fo;
        if (f >= TF) continue;
        const int idx = sidx[fo];                      // LDS broadcast
        float4 v = make_float4(0.f, 0.f, 0.f, 0.f);
        if (idx >= 0) v = srcb[(idx << 7) + c];
        out4[(((size_t)b * TF + f) << 7) + c] = v;
    }
}

extern "C" void kernel_launch(void* const* d_in, const int* in_sizes, int n_in,
                              void* d_out, int out_size, void* d_ws, size_t ws_size,
                              hipStream_t stream) {
    const float* batch = (const float*)d_in[0];
    const float* pred  = (const float*)d_in[1];
    float* out = (float*)d_out;

    lr_fused<<<GRID, 256, 0, stream>>>(pred, (const float4*)batch, (float4*)out);
}

// Round 5
// 27.107 us; speedup vs baseline: 1.8174x; 1.0201x over previous
//
#include <hip/hip_runtime.h>

#define NB 64
#define NT 512
#define HIDDEN 512
#define TF 861            // 22050*10/256
#define CHUNKS 32
#define FPC 27            // frames per chunk (last chunk: 24 real)
#define GRID (NB * CHUNKS)   // 2048, divisible by 8, = 8 blocks/CU

// Fully fused. Per block: shuffle-scan the row's 512 durations (2/thread),
// then SCATTER frame->idx directly from registers (element e covers frames
// [ends[e-1], ends[e])), then stream-copy 27 frames (1 frame per wave-iter).
__global__ __launch_bounds__(256) void lr_fused(const float* __restrict__ pred,
                                                const float4* __restrict__ batch4,
                                                float4* __restrict__ out4) {
    __shared__ int wsum[4];
    __shared__ int sidx[FPC];

    // XCD-chunked swizzle: each XCD owns a contiguous (b,chunk) range
    const int bid = blockIdx.x;
    const int sid = (bid & 7) * (GRID >> 3) + (bid >> 3);
    const int b = sid >> 5;           // CHUNKS == 32
    const int chunk = sid & 31;
    const int base = chunk * FPC;

    const int t = threadIdx.x;
    const int lane = t & 63;
    const int wid = t >> 6;

    // ---- duration scan: 512 entries, 2 per thread, shuffle-based ----
    float2 p2 = ((const float2*)(pred + b * NT))[t];
    int d0 = (int)rintf(fminf(fmaxf(p2.x, 1.f), 10.f));   // round-half-even
    int d1 = (int)rintf(fminf(fmaxf(p2.y, 1.f), 10.f));
    int x = d0 + d1;
    #pragma unroll
    for (int off = 1; off < 64; off <<= 1) {
        int y = __shfl_up(x, off, 64);
        if (lane >= off) x += y;
    }
    if (lane == 63) wsum[wid] = x;
    if (t < FPC) sidx[t] = -1;
    __syncthreads();
    int prefix = 0;
    #pragma unroll
    for (int w = 0; w < 3; ++w)
        if (w < wid) prefix += wsum[w];
    x += prefix;

    // ---- scatter: ends[2t-1..2t+1] are in registers ----
    const int end1   = x;             // ends[2t+1]
    const int start1 = x - d1;        // ends[2t]
    const int start0 = start1 - d0;   // ends[2t-1]
    const int wend = min(base + FPC, TF);
    {
        int lo = max(start0, base), hi = min(start1, wend);
        for (int f = lo; f < hi; ++f) sidx[f - base] = 2 * t;
        lo = max(start1, base); hi = min(end1, wend);
        for (int f = lo; f < hi; ++f) sidx[f - base] = 2 * t + 1;
    }
    __syncthreads();

    // ---- streaming copy: one frame (2 KB) per wave per iteration ----
    const float4* srcb = batch4 + ((size_t)b << 16);   // b*512*128
    #pragma unroll 2
    for (int fo = wid; fo < FPC; fo += 4) {
        const int f = base + fo;
        if (f >= TF) break;                // only last chunk; monotone in fo
        const int idx = sidx[fo];          // LDS broadcast
        float4 v0 = make_float4(0.f, 0.f, 0.f, 0.f);
        float4 v1 = v0;
        if (idx >= 0) {
            const float4* src = srcb + ((size_t)idx << 7);
            v0 = src[lane];
            v1 = src[lane + 64];
        }
        float4* dst = out4 + (((size_t)b * TF + f) << 7);
        dst[lane] = v0;
        dst[lane + 64] = v1;
    }
}

extern "C" void kernel_launch(void* const* d_in, const int* in_sizes, int n_in,
                              void* d_out, int out_size, void* d_ws, size_t ws_size,
                              hipStream_t stream) {
    const float* batch = (const float*)d_in[0];
    const float* pred  = (const float*)d_in[1];
    float* out = (float*)d_out;

    lr_fused<<<GRID, 256, 0, stream>>>(pred, (const float4*)batch, (float4*)out);
}